// Round 1
// 1465.405 us; speedup vs baseline: 1.0298x; 1.0298x over previous
//
#include <hip/hip_runtime.h>
#include <stdint.h>

#define B_  8
#define S_  2048
#define DM  1024
#define NI  4096
#define NP  2048
#define DR  256
#define H2  512
#define KI  2048
#define KP  1024
#define LDW 40   // LDS row stride in ushorts (gemm3 only)

typedef __attribute__((ext_vector_type(8))) short bf16x8;
typedef __attribute__((ext_vector_type(4))) float f32x4;
typedef unsigned short ushort;
typedef unsigned int uint;

__device__ __forceinline__ float gelu_erf(float v){
    return 0.5f * v * (1.0f + erff(v * 0.7071067811865476f));
}
__device__ __forceinline__ ushort f2b(float f){      // fp32 -> bf16 bits, RNE
    union { float f; uint u; } a; a.f = f;
    uint r = a.u + 0x7fffu + ((a.u >> 16) & 1u);
    return (ushort)(r >> 16);
}
__device__ __forceinline__ float b2f(ushort u){
    union { uint u; float f; } a; a.u = ((uint)u) << 16; return a.f;
}
// 8 consecutive floats -> 8 hi bf16 (uint4) + 8 lo bf16 (uint4)
__device__ __forceinline__ void cvt8(const float* p, uint4& H, uint4& L){
    uint h[4], l[4];
    #pragma unroll
    for(int i = 0; i < 4; i++){
        ushort h0 = f2b(p[2*i]);   float f0 = b2f(h0); ushort l0 = f2b(p[2*i]   - f0);
        ushort h1 = f2b(p[2*i+1]); float f1 = b2f(h1); ushort l1 = f2b(p[2*i+1] - f1);
        h[i] = (uint)h0 | ((uint)h1 << 16);
        l[i] = (uint)l0 | ((uint)l1 << 16);
    }
    H = uint4{h[0],h[1],h[2],h[3]};
    L = uint4{l[0],l[1],l[2],l[3]};
}
// async global->LDS, 16B per lane. LDS dest is wave-uniform base + lane*16.
__device__ __forceinline__ void gload_lds16(const void* g, void* l){
    __builtin_amdgcn_global_load_lds((const __attribute__((address_space(1))) void*)g,
                                     (__attribute__((address_space(3))) void*)l, 16, 0, 0);
}

// ---------------- pre-split fp32 -> hi/lo bf16 ------------------------------
__global__ __launch_bounds__(256) void k_cvt(const float* __restrict__ src,
                                             ushort* __restrict__ hi,
                                             ushort* __restrict__ lo){
    size_t idx = (size_t)blockIdx.x*256 + threadIdx.x;
    float f[8];
    *(float4*)(f)     = ((const float4*)src)[idx*2];
    *(float4*)(f + 4) = ((const float4*)src)[idx*2 + 1];
    uint4 H, L; cvt8(f, H, L);
    ((uint4*)hi)[idx] = H;
    ((uint4*)lo)[idx] = L;
}

// ---------------- Router (all fp32) -----------------------------------------
__global__ __launch_bounds__(256) void k_gpart(const float* __restrict__ x,
                                               float* __restrict__ gpart){
    int b = blockIdx.x >> 4, ch = blockIdx.x & 15;
    const float4* xb = (const float4*)(x + ((size_t)b*S_ + (size_t)ch*128) * DM);
    int t = threadIdx.x;
    float4 m = xb[t];
    for(int r = 1; r < 128; r++){
        float4 v = xb[(size_t)r*(DM/4) + t];
        m.x = fmaxf(m.x, v.x); m.y = fmaxf(m.y, v.y);
        m.z = fmaxf(m.z, v.z); m.w = fmaxf(m.w, v.w);
    }
    ((float4*)(gpart + (size_t)(b*16 + ch)*DM))[t] = m;
}

__global__ __launch_bounds__(256) void k_h(const float* __restrict__ gpart,
                                           const float* __restrict__ W1,
                                           const float* __restrict__ b1,
                                           float* __restrict__ h){
    __shared__ float g[DM];
    int b = blockIdx.x >> 3, ig = blockIdx.x & 7;
    int t = threadIdx.x;
    for(int d = t; d < DM; d += 256){
        float m = gpart[(size_t)(b*16)*DM + d];
        for(int c = 1; c < 16; c++) m = fmaxf(m, gpart[(size_t)(b*16 + c)*DM + d]);
        g[d] = m;
    }
    __syncthreads();
    int i  = ig*64 + (t >> 2);
    int dq = (t & 3) * 256;
    const float* wr = W1 + (size_t)i*DM + dq;
    const float* gg = g + dq;
    float s = 0.f;
    for(int d = 0; d < 256; d++) s = fmaf(gg[d], wr[d], s);
    s += __shfl_xor(s, 1);
    s += __shfl_xor(s, 2);
    if((t & 3) == 0) h[b*H2 + i] = gelu_erf(s + b1[i]);
}

__global__ __launch_bounds__(256) void k_query(const float* __restrict__ h,
                                               const float* __restrict__ lng,
                                               const float* __restrict__ lnb,
                                               const float* __restrict__ W2,
                                               const float* __restrict__ b2,
                                               float* __restrict__ query){
    __shared__ float hn[H2];
    __shared__ float red[4];
    int b = blockIdx.x >> 2, qg = blockIdx.x & 3;
    int t = threadIdx.x;
    float v0 = h[b*H2 + t], v1 = h[b*H2 + 256 + t];
    float s = v0 + v1;
    for(int o = 32; o > 0; o >>= 1) s += __shfl_down(s, o);
    if((t & 63) == 0) red[t >> 6] = s;
    __syncthreads();
    float mean = (red[0] + red[1] + red[2] + red[3]) * (1.f/H2);
    __syncthreads();
    float d0 = v0 - mean, d1 = v1 - mean;
    float sq = d0*d0 + d1*d1;
    for(int o = 32; o > 0; o >>= 1) sq += __shfl_down(sq, o);
    if((t & 63) == 0) red[t >> 6] = sq;
    __syncthreads();
    float var  = (red[0] + red[1] + red[2] + red[3]) * (1.f/H2);
    float rstd = rsqrtf(var + 1e-5f);
    hn[t]       = d0*rstd*lng[t]       + lnb[t];
    hn[256 + t] = d1*rstd*lng[256 + t] + lnb[256 + t];
    __syncthreads();
    int q  = qg*64 + (t >> 2);
    int iq = (t & 3) * 128;
    const float* wr = W2 + (size_t)q*H2 + iq;
    float acc = 0.f;
    for(int i2 = 0; i2 < 128; i2++) acc = fmaf(hn[iq + i2], wr[i2], acc);
    acc += __shfl_xor(acc, 1);
    acc += __shfl_xor(acc, 2);
    if((t & 3) == 0) query[b*DR + q] = acc + b2[q];
}

__global__ __launch_bounds__(256) void k_logits(const float* __restrict__ query,
                                                const float* __restrict__ nk,
                                                float* __restrict__ logits){
    __shared__ float q[DR];
    int b = blockIdx.x >> 4, ng = blockIdx.x & 15;
    int t = threadIdx.x;
    if(t < DR) q[t] = query[b*DR + t];
    __syncthreads();
    int n = ng*256 + t;
    const float* kr = nk + (size_t)n*DR;
    float s = 0.f;
    for(int i = 0; i < DR; i++) s = fmaf(q[i], kr[i], s);
    logits[b*NI + n] = s * 0.0625f;
}

// ------- Top-k SET selection, SORTED ascending output (scan-based) ----------
template<int N_, int KSEL>
__global__ __launch_bounds__(256) void k_topk(const float* __restrict__ vals,
                                              int* __restrict__ idxout){
    __shared__ unsigned u[N_];
    __shared__ int redc[4];
    __shared__ int sc[256];
    int t = threadIdx.x;
    size_t vbase = (size_t)blockIdx.x * N_;
    size_t obase = (size_t)blockIdx.x * KSEL;
    for(int i = t; i < N_; i += 256){
        unsigned bits = __float_as_uint(vals[vbase + i]);
        u[i] = (bits & 0x80000000u) ? ~bits : (bits | 0x80000000u);
    }
    __syncthreads();
    unsigned lo = 0u, hi = 0xFFFFFFFFu;
    while(lo < hi){
        unsigned mid = lo + (unsigned)((((unsigned long long)(hi - lo)) + 1ull) >> 1);
        int c = 0;
        for(int i = t; i < N_; i += 256) c += (u[i] >= mid) ? 1 : 0;
        for(int o = 32; o > 0; o >>= 1) c += __shfl_down(c, o);
        if((t & 63) == 0) redc[t >> 6] = c;
        __syncthreads();
        int tot = redc[0] + redc[1] + redc[2] + redc[3];
        if(tot >= KSEL) lo = mid; else hi = mid - 1;
        __syncthreads();
    }
    unsigned T = lo;
    const int PER = N_ / 256;
    int base = t * PER;
    int lgt = 0, leq = 0;
    for(int j = 0; j < PER; j++){
        unsigned v = u[base + j];
        lgt += (v > T) ? 1 : 0; leq += (v == T) ? 1 : 0;
    }
    sc[t] = (lgt << 16) | leq;
    __syncthreads();
    for(int o = 1; o < 256; o <<= 1){
        int add = (t >= o) ? sc[t - o] : 0;
        __syncthreads();
        sc[t] += add;
        __syncthreads();
    }
    int need = KSEL - (sc[255] >> 16);
    int ex = (t == 0) ? 0 : sc[t - 1];
    int pos = (ex >> 16) + ((ex & 0xffff) < need ? (ex & 0xffff) : need);
    int eq = ex & 0xffff;
    for(int j = 0; j < PER; j++){
        unsigned v = u[base + j];
        if(v > T){ idxout[obase + pos++] = base + j; }
        else if(v == T){ if(eq < need){ idxout[obase + pos++] = base + j; } eq++; }
    }
}

// ------- GEMM1 (G batches): split(gelu(x_b @ patt[iidx_b]^T)) -> selh/sell --
// Pre-split bf16 hi/lo inputs; global_load_lds dbuf pipeline, counted vmcnt.
__global__ __launch_bounds__(256) void k_gemm1(const ushort* __restrict__ xh,
                                               const ushort* __restrict__ xl,
                                               const ushort* __restrict__ ph,
                                               const ushort* __restrict__ pl,
                                               const int* __restrict__ iidx,
                                               ushort* __restrict__ selh,
                                               ushort* __restrict__ sell, int b0){
    __shared__ __align__(16) ushort Ah[2][128*32], Al[2][128*32], Bh[2][128*32], Bl[2][128*32];
    __shared__ int rowmap[128];
    int t = threadIdx.x;
    int g = blockIdx.x >> 8, rest = blockIdx.x & 255;
    int b = b0 + g;
    int mb = rest >> 4, nb = rest & 15;
    int m0 = mb*128, n0 = nb*128;
    ushort* selh_g = selh + (size_t)g*S_*KI;
    ushort* sell_g = sell + (size_t)g*S_*KI;
    if(t < 128) rowmap[t] = iidx[(size_t)b*KI + n0 + t];
    __syncthreads();
    int w = t >> 6, l = t & 63;
    int lr = l >> 2, lc = l & 3;
    int r0 = 32*w + lr, r1 = r0 + 16;
    const ushort* pAh0 = xh + ((size_t)b*S_ + m0 + r0)*DM + lc*8;
    const ushort* pAh1 = xh + ((size_t)b*S_ + m0 + r1)*DM + lc*8;
    const ushort* pAl0 = xl + ((size_t)b*S_ + m0 + r0)*DM + lc*8;
    const ushort* pAl1 = xl + ((size_t)b*S_ + m0 + r1)*DM + lc*8;
    const ushort* pBh0 = ph + (size_t)rowmap[r0]*DM + lc*8;
    const ushort* pBh1 = ph + (size_t)rowmap[r1]*DM + lc*8;
    const ushort* pBl0 = pl + (size_t)rowmap[r0]*DM + lc*8;
    const ushort* pBl1 = pl + (size_t)rowmap[r1]*DM + lc*8;
    int d0 = w*1024, d1 = d0 + 512;      // ushort index: rows 32w.. / 32w+16..
    #define STG1(BUF, KO) do{ \
        gload_lds16(pAh0 + (KO), &Ah[BUF][d0]); \
        gload_lds16(pAh1 + (KO), &Ah[BUF][d1]); \
        gload_lds16(pAl0 + (KO), &Al[BUF][d0]); \
        gload_lds16(pAl1 + (KO), &Al[BUF][d1]); \
        gload_lds16(pBh0 + (KO), &Bh[BUF][d0]); \
        gload_lds16(pBh1 + (KO), &Bh[BUF][d1]); \
        gload_lds16(pBl0 + (KO), &Bl[BUF][d0]); \
        gload_lds16(pBl1 + (KO), &Bl[BUF][d1]); \
    }while(0)
    STG1(0, 0);
    int lm = l & 15, q = l >> 4;
    int mbase = (w >> 1)*64, nbase = (w & 1)*64;
    f32x4 acc[4][4];
    #pragma unroll
    for(int i = 0; i < 4; i++)
      #pragma unroll
      for(int j = 0; j < 4; j++) acc[i][j] = f32x4{0.f,0.f,0.f,0.f};
    int cur = 0;
    for(int k0 = 0; k0 < DM; k0 += 32){
        if(k0 + 32 < DM){
            STG1(cur^1, k0 + 32);
            asm volatile("s_waitcnt vmcnt(8)" ::: "memory");
        }else{
            asm volatile("s_waitcnt vmcnt(0)" ::: "memory");
        }
        __builtin_amdgcn_s_barrier();
        asm volatile("" ::: "memory");
        bf16x8 ahf[4], alf[4];
        #pragma unroll
        for(int mt = 0; mt < 4; mt++){
            ahf[mt] = *(const bf16x8*)(&Ah[cur][(mbase + mt*16 + lm)*32 + q*8]);
            alf[mt] = *(const bf16x8*)(&Al[cur][(mbase + mt*16 + lm)*32 + q*8]);
        }
        __builtin_amdgcn_s_setprio(1);
        #pragma unroll
        for(int nt = 0; nt < 4; nt++){
            bf16x8 bhf = *(const bf16x8*)(&Bh[cur][(nbase + nt*16 + lm)*32 + q*8]);
            bf16x8 blf = *(const bf16x8*)(&Bl[cur][(nbase + nt*16 + lm)*32 + q*8]);
            #pragma unroll
            for(int mt = 0; mt < 4; mt++){
                acc[mt][nt] = __builtin_amdgcn_mfma_f32_16x16x32_bf16(ahf[mt], bhf, acc[mt][nt], 0, 0, 0);
                acc[mt][nt] = __builtin_amdgcn_mfma_f32_16x16x32_bf16(ahf[mt], blf, acc[mt][nt], 0, 0, 0);
                acc[mt][nt] = __builtin_amdgcn_mfma_f32_16x16x32_bf16(alf[mt], bhf, acc[mt][nt], 0, 0, 0);
            }
        }
        __builtin_amdgcn_s_setprio(0);
        asm volatile("s_waitcnt lgkmcnt(0)" ::: "memory");
        __builtin_amdgcn_s_barrier();
        asm volatile("" ::: "memory");
        cur ^= 1;
    }
    #undef STG1
    #pragma unroll
    for(int mt = 0; mt < 4; mt++)
      #pragma unroll
      for(int nt = 0; nt < 4; nt++){
        int col = n0 + nbase + nt*16 + lm;
        #pragma unroll
        for(int i = 0; i < 4; i++){
            int row = m0 + mbase + mt*16 + q*4 + i;
            float gv = gelu_erf(acc[mt][nt][i]);
            ushort hbits = f2b(gv);
            selh_g[(size_t)row*KI + col] = hbits;
            sell_g[(size_t)row*KI + col] = f2b(gv - b2f(hbits));
        }
      }
}

// ------- Gather (G batches): split pw columns -> wh/wl; zero scores ---------
__global__ __launch_bounds__(256) void k_gather_wsel(const float* __restrict__ pw,
                                                     const int* __restrict__ iidx,
                                                     ushort* __restrict__ wh,
                                                     ushort* __restrict__ wl,
                                                     float* __restrict__ scores, int b0){
    __shared__ int kidx[KI];
    int g = blockIdx.x >> 8, pc = blockIdx.x & 255;
    int b = b0 + g;
    ushort* wh_g = wh + (size_t)g*NP*KI;
    ushort* wl_g = wl + (size_t)g*NP*KI;
    int t = threadIdx.x;
    for(int i = t; i < KI; i += 256) kidx[i] = iidx[(size_t)b*KI + i];
    if(t < 8) scores[(size_t)b*NP + pc*8 + t] = 0.f;
    __syncthreads();
    for(int r2 = 0; r2 < 8; r2++){
        int p = pc*8 + r2;
        const float* row = pw + (size_t)p*NI;
        for(int j = t; j < KI; j += 256){
            float v = row[kidx[j]];                 // kidx sorted -> good locality
            ushort hb = f2b(v);
            wh_g[(size_t)p*KI + j] = hb;
            wl_g[(size_t)p*KI + j] = f2b(v - b2f(hb));
        }
    }
}

// ------- GEMM2 (G batches): acts=gelu(selin @ wsel^T) bf16 + col sums -------
// Inputs already bf16 hi/lo; global_load_lds dbuf pipeline, counted vmcnt.
__global__ __launch_bounds__(256) void k_gemm2(const ushort* __restrict__ selh,
                                               const ushort* __restrict__ sell,
                                               const ushort* __restrict__ wh,
                                               const ushort* __restrict__ wl,
                                               ushort* __restrict__ acts,
                                               float* __restrict__ scores, int b0){
    __shared__ __align__(16) ushort Ah[2][128*32], Al[2][128*32], Bh[2][128*32], Bl[2][128*32];
    __shared__ float colsum[128];
    int t = threadIdx.x;
    int g = blockIdx.x >> 8, rest = blockIdx.x & 255;
    int b = b0 + g;
    int mb = rest >> 4, nb = rest & 15;
    int m0 = mb*128, n0 = nb*128;
    const ushort* selh_g = selh + (size_t)g*S_*KI;
    const ushort* sell_g = sell + (size_t)g*S_*KI;
    const ushort* wh_g   = wh   + (size_t)g*NP*KI;
    const ushort* wl_g   = wl   + (size_t)g*NP*KI;
    ushort* acts_g = acts + (size_t)g*S_*NP;
    int w = t >> 6, l = t & 63;
    int lr = l >> 2, lc = l & 3;
    int r0 = 32*w + lr, r1 = r0 + 16;
    const ushort* pAh0 = selh_g + (size_t)(m0 + r0)*KI + lc*8;
    const ushort* pAh1 = selh_g + (size_t)(m0 + r1)*KI + lc*8;
    const ushort* pAl0 = sell_g + (size_t)(m0 + r0)*KI + lc*8;
    const ushort* pAl1 = sell_g + (size_t)(m0 + r1)*KI + lc*8;
    const ushort* pBh0 = wh_g + (size_t)(n0 + r0)*KI + lc*8;
    const ushort* pBh1 = wh_g + (size_t)(n0 + r1)*KI + lc*8;
    const ushort* pBl0 = wl_g + (size_t)(n0 + r0)*KI + lc*8;
    const ushort* pBl1 = wl_g + (size_t)(n0 + r1)*KI + lc*8;
    int d0 = w*1024, d1 = d0 + 512;
    #define STG2(BUF, KO) do{ \
        gload_lds16(pAh0 + (KO), &Ah[BUF][d0]); \
        gload_lds16(pAh1 + (KO), &Ah[BUF][d1]); \
        gload_lds16(pAl0 + (KO), &Al[BUF][d0]); \
        gload_lds16(pAl1 + (KO), &Al[BUF][d1]); \
        gload_lds16(pBh0 + (KO), &Bh[BUF][d0]); \
        gload_lds16(pBh1 + (KO), &Bh[BUF][d1]); \
        gload_lds16(pBl0 + (KO), &Bl[BUF][d0]); \
        gload_lds16(pBl1 + (KO), &Bl[BUF][d1]); \
    }while(0)
    STG2(0, 0);
    int lm = l & 15, q = l >> 4;
    int mbase = (w >> 1)*64, nbase = (w & 1)*64;
    f32x4 acc[4][4];
    #pragma unroll
    for(int i = 0; i < 4; i++)
      #pragma unroll
      for(int j = 0; j < 4; j++) acc[i][j] = f32x4{0.f,0.f,0.f,0.f};
    int cur = 0;
    for(int k0 = 0; k0 < KI; k0 += 32){
        if(k0 + 32 < KI){
            STG2(cur^1, k0 + 32);
            asm volatile("s_waitcnt vmcnt(8)" ::: "memory");
        }else{
            asm volatile("s_waitcnt vmcnt(0)" ::: "memory");
        }
        __builtin_amdgcn_s_barrier();
        asm volatile("" ::: "memory");
        bf16x8 ahf[4], alf[4];
        #pragma unroll
        for(int mt = 0; mt < 4; mt++){
            ahf[mt] = *(const bf16x8*)(&Ah[cur][(mbase + mt*16 + lm)*32 + q*8]);
            alf[mt] = *(const bf16x8*)(&Al[cur][(mbase + mt*16 + lm)*32 + q*8]);
        }
        __builtin_amdgcn_s_setprio(1);
        #pragma unroll
        for(int nt = 0; nt < 4; nt++){
            bf16x8 bhf = *(const bf16x8*)(&Bh[cur][(nbase + nt*16 + lm)*32 + q*8]);
            bf16x8 blf = *(const bf16x8*)(&Bl[cur][(nbase + nt*16 + lm)*32 + q*8]);
            #pragma unroll
            for(int mt = 0; mt < 4; mt++){
                acc[mt][nt] = __builtin_amdgcn_mfma_f32_16x16x32_bf16(ahf[mt], bhf, acc[mt][nt], 0, 0, 0);
                acc[mt][nt] = __builtin_amdgcn_mfma_f32_16x16x32_bf16(ahf[mt], blf, acc[mt][nt], 0, 0, 0);
                acc[mt][nt] = __builtin_amdgcn_mfma_f32_16x16x32_bf16(alf[mt], bhf, acc[mt][nt], 0, 0, 0);
            }
        }
        __builtin_amdgcn_s_setprio(0);
        asm volatile("s_waitcnt lgkmcnt(0)" ::: "memory");
        __builtin_amdgcn_s_barrier();
        asm volatile("" ::: "memory");
        cur ^= 1;
    }
    #undef STG2
    if(t < 128) colsum[t] = 0.f;
    __syncthreads();
    #pragma unroll
    for(int mt = 0; mt < 4; mt++)
      #pragma unroll
      for(int nt = 0; nt < 4; nt++){
        int cb = nbase + nt*16 + lm;
        float s4 = 0.f;
        #pragma unroll
        for(int i = 0; i < 4; i++){
            int row = m0 + mbase + mt*16 + q*4 + i;
            float gv = gelu_erf(acc[mt][nt][i]);
            s4 += gv;
            acts_g[(size_t)row*NP + n0 + cb] = f2b(gv);
        }
        atomicAdd(&colsum[cb], s4);
      }
    __syncthreads();
    if(t < 128) atomicAdd(&scores[(size_t)b*NP + n0 + t], colsum[t]);
}

// ------- Gather (G batches): selacts[s][j] = acts[s][pix[j]] ----------------
__global__ __launch_bounds__(256) void k_gather_selacts(const ushort* __restrict__ acts,
                                                        const int* __restrict__ pidx,
                                                        ushort* __restrict__ selacts, int b0){
    __shared__ int pix[KP];
    int g = blockIdx.x >> 6, sc_ = blockIdx.x & 63;
    int b = b0 + g;
    const ushort* acts_g = acts + (size_t)g*S_*NP;
    ushort* selacts_g = selacts + (size_t)g*S_*KP;
    int t = threadIdx.x;
    for(int i = t; i < KP; i += 256) pix[i] = pidx[(size_t)b*KP + i];
    __syncthreads();
    const ushort* Ab = acts_g    + ((size_t)sc_*32)*NP;
    ushort*       Ob = selacts_g + ((size_t)sc_*32)*KP;
    for(int r2 = 0; r2 < 32; r2++){
        for(int j = t; j < KP; j += 256)
            Ob[(size_t)r2*KP + j] = Ab[(size_t)r2*NP + pix[j]];
    }
}

// ------- GEMM3 (G batches): out_b = selacts(bf16) @ pout[pix] ---------------
__global__ __launch_bounds__(256) void k_gemm3(const ushort* __restrict__ selacts,
                                               const float* __restrict__ pout,
                                               const int* __restrict__ pidx,
                                               float* __restrict__ out, int b0){
    __shared__ __align__(16) ushort As[128*LDW], Bs[128*LDW];
    __shared__ int pix[KP];
    int t = threadIdx.x;
    int g = blockIdx.x >> 7, rest = blockIdx.x & 127;
    int b = b0 + g;
    int mb = rest >> 3, nb = rest & 7;
    int m0 = mb*128, n0 = nb*128;
    const ushort* selacts_g = selacts + (size_t)g*S_*KP;
    for(int i = t; i < KP; i += 256) pix[i] = pidx[(size_t)b*KP + i];
    __syncthreads();
    int r = t & 127, half = t >> 7;
    const ushort* ag = selacts_g + (size_t)(m0 + r)*KP + half*16;
    int kk = t >> 3, nc = (t & 7)*16;                    // B: 32 k-rows x 128 n-cols
    uint4 A0 = *(const uint4*)(ag), A1 = *(const uint4*)(ag + 8);
    float4 fb[4];
    {
        const float* bg = pout + (size_t)pix[kk]*DM + n0 + nc;
        #pragma unroll
        for(int i = 0; i < 4; i++) fb[i] = *(const float4*)(bg + i*4);
    }
    int w = t >> 6, lane = t & 63;
    int mbase = (w >> 1)*64, nbase = (w & 1)*64;
    int lm = lane & 15, q = lane >> 4;
    f32x4 acc[4][4];
    #pragma unroll
    for(int i = 0; i < 4; i++)
      #pragma unroll
      for(int j = 0; j < 4; j++) acc[i][j] = f32x4{0.f,0.f,0.f,0.f};
    for(int k0 = 0; k0 < KP; k0 += 32){
        __syncthreads();
        *(uint4*)(As + r*LDW + half*16)     = A0;
        *(uint4*)(As + r*LDW + half*16 + 8) = A1;
        {
            const float* pf = (const float*)fb;
            #pragma unroll
            for(int c = 0; c < 16; c++) Bs[(nc + c)*LDW + kk] = f2b(pf[c]);
        }
        __syncthreads();
        if(k0 + 32 < KP){
            ag += 32;
            A0 = *(const uint4*)(ag); A1 = *(const uint4*)(ag + 8);
            const float* bg = pout + (size_t)pix[k0 + 32 + kk]*DM + n0 + nc;
            #pragma unroll
            for(int i = 0; i < 4; i++) fb[i] = *(const float4*)(bg + i*4);
        }
        bf16x8 af[4];
        #pragma unroll
        for(int mt = 0; mt < 4; mt++)
            af[mt] = *(const bf16x8*)(As + (mbase + mt*16 + lm)*LDW + q*8);
        #pragma unroll
        for(int nt = 0; nt < 4; nt++){
            bf16x8 bf = *(const bf16x8*)(Bs + (nbase + nt*16 + lm)*LDW + q*8);
            #pragma unroll
            for(int mt = 0; mt < 4; mt++)
                acc[mt][nt] = __builtin_amdgcn_mfma_f32_16x16x32_bf16(af[mt], bf, acc[mt][nt], 0, 0, 0);
        }
    }
    float* Cb = out + (size_t)b*S_*DM;
    #pragma unroll
    for(int mt = 0; mt < 4; mt++)
      #pragma unroll
      for(int nt = 0; nt < 4; nt++){
        int col = n0 + nbase + nt*16 + lm;
        #pragma unroll
        for(int i = 0; i < 4; i++){
            int row = m0 + mbase + mt*16 + q*4 + i;
            Cb[(size_t)row*DM + col] = acc[mt][nt][i];
        }
      }
}

// ---------------- launch ----------------------------------------------------
extern "C" void kernel_launch(void* const* d_in, const int* in_sizes, int n_in,
                              void* d_out, int out_size, void* d_ws, size_t ws_size,
                              hipStream_t stream){
    const float* x    = (const float*)d_in[0];
    const float* W1   = (const float*)d_in[3];
    const float* b1   = (const float*)d_in[4];
    const float* lng  = (const float*)d_in[5];
    const float* lnb  = (const float*)d_in[6];
    const float* W2   = (const float*)d_in[7];
    const float* b2   = (const float*)d_in[8];
    const float* nk   = (const float*)d_in[9];
    const float* patt = (const float*)d_in[10];
    const float* pw   = (const float*)d_in[11];
    const float* pout = (const float*)d_in[12];
    float* out = (float*)d_out;

    auto al256 = [](size_t v){ return (v + 255) & ~(size_t)255; };
    const size_t fixed =
        al256((size_t)B_*16*DM*4) + al256((size_t)B_*H2*4) + al256((size_t)B_*DR*4) +
        al256((size_t)B_*NI*4)    + al256((size_t)B_*KI*4) + al256((size_t)B_*NP*4) +
        al256((size_t)B_*KP*4) +
        2*al256((size_t)B_*S_*DM*2) + 2*al256((size_t)NI*DM*2);
    const size_t perb = (size_t)S_*KI*2*2 + (size_t)NP*KI*2*2 + (size_t)S_*NP*2 + (size_t)S_*KP*2 + 6*256;
    int G = 4;                                   // ws_size-constant across calls -> capture-safe
    while(G > 1 && fixed + (size_t)G*perb > ws_size) G >>= 1;
    if(fixed + (size_t)G*perb > ws_size) return; // clean-fail guard

    char* wsp = (char*)d_ws;
    size_t off = 0;
    auto alloc = [&](size_t bytes) -> void* {
        void* p = wsp + off;
        off += (bytes + 255) & ~(size_t)255;
        return p;
    };
    float*  gpart   = (float*) alloc((size_t)B_*16*DM*4);
    float*  h       = (float*) alloc((size_t)B_*H2*4);
    float*  query   = (float*) alloc((size_t)B_*DR*4);
    float*  logits  = (float*) alloc((size_t)B_*NI*4);
    int*    iidx    = (int*)   alloc((size_t)B_*KI*4);
    float*  scores  = (float*) alloc((size_t)B_*NP*4);
    int*    pidx    = (int*)   alloc((size_t)B_*KP*4);
    ushort* xh      = (ushort*)alloc((size_t)B_*S_*DM*2);
    ushort* xl      = (ushort*)alloc((size_t)B_*S_*DM*2);
    ushort* patth   = (ushort*)alloc((size_t)NI*DM*2);
    ushort* pattl   = (ushort*)alloc((size_t)NI*DM*2);
    ushort* selh    = (ushort*)alloc((size_t)G*S_*KI*2);
    ushort* sell    = (ushort*)alloc((size_t)G*S_*KI*2);
    ushort* wselh   = (ushort*)alloc((size_t)G*NP*KI*2);
    ushort* wsell   = (ushort*)alloc((size_t)G*NP*KI*2);
    ushort* acts    = (ushort*)alloc((size_t)G*S_*NP*2);
    ushort* selacts = (ushort*)alloc((size_t)G*S_*KP*2);

    dim3 blk(256);
    k_cvt   <<<(B_*S_*DM/8)/256, blk, 0, stream>>>(x, xh, xl);
    k_cvt   <<<(NI*DM/8)/256,    blk, 0, stream>>>(patt, patth, pattl);
    k_gpart <<<128, blk, 0, stream>>>(x, gpart);
    k_h     <<<64,  blk, 0, stream>>>(gpart, W1, b1, h);
    k_query <<<32,  blk, 0, stream>>>(h, lng, lnb, W2, b2, query);
    k_logits<<<128, blk, 0, stream>>>(query, nk, logits);
    k_topk<NI, KI><<<B_, blk, 0, stream>>>(logits, iidx);
    for(int b0 = 0; b0 < B_; b0 += G){
        k_gemm1        <<<G*256, blk, 0, stream>>>(xh, xl, patth, pattl, iidx, selh, sell, b0);
        k_gather_wsel  <<<G*256, blk, 0, stream>>>(pw, iidx, wselh, wsell, scores, b0);
        k_gemm2        <<<G*256, blk, 0, stream>>>(selh, sell, wselh, wsell, acts, scores, b0);
        k_topk<NP, KP> <<<G,     blk, 0, stream>>>(scores + (size_t)b0*NP, pidx + (size_t)b0*KP);
        k_gather_selacts<<<G*64, blk, 0, stream>>>(acts, pidx, selacts, b0);
        k_gemm3        <<<G*128, blk, 0, stream>>>(selacts, pout, pidx, out, b0);
    }
}

// Round 2
// 1296.826 us; speedup vs baseline: 1.1636x; 1.1300x over previous
//
#include <hip/hip_runtime.h>
#include <stdint.h>

#define B_  8
#define S_  2048
#define DM  1024
#define NI  4096
#define NP  2048
#define DR  256
#define H2  512
#define KI  2048
#define KP  1024
#define LDW 40   // LDS row stride in ushorts (gemm3 B only; 80B rows -> 16B-aligned b128 reads)

typedef __attribute__((ext_vector_type(8))) short bf16x8;
typedef __attribute__((ext_vector_type(4))) float f32x4;
typedef unsigned short ushort;
typedef unsigned int uint;

__device__ __forceinline__ float gelu_erf(float v){
    return 0.5f * v * (1.0f + erff(v * 0.7071067811865476f));
}
__device__ __forceinline__ ushort f2b(float f){      // fp32 -> bf16 bits, RNE
    union { float f; uint u; } a; a.f = f;
    uint r = a.u + 0x7fffu + ((a.u >> 16) & 1u);
    return (ushort)(r >> 16);
}
__device__ __forceinline__ float b2f(ushort u){
    union { uint u; float f; } a; a.u = ((uint)u) << 16; return a.f;
}
// 8 consecutive floats -> 8 hi bf16 (uint4) + 8 lo bf16 (uint4)
__device__ __forceinline__ void cvt8(const float* p, uint4& H, uint4& L){
    uint h[4], l[4];
    #pragma unroll
    for(int i = 0; i < 4; i++){
        ushort h0 = f2b(p[2*i]);   float f0 = b2f(h0); ushort l0 = f2b(p[2*i]   - f0);
        ushort h1 = f2b(p[2*i+1]); float f1 = b2f(h1); ushort l1 = f2b(p[2*i+1] - f1);
        h[i] = (uint)h0 | ((uint)h1 << 16);
        l[i] = (uint)l0 | ((uint)l1 << 16);
    }
    H = uint4{h[0],h[1],h[2],h[3]};
    L = uint4{l[0],l[1],l[2],l[3]};
}
// async global->LDS, 16B per lane. LDS dest is wave-uniform base + lane*16.
__device__ __forceinline__ void gload_lds16(const void* g, void* l){
    __builtin_amdgcn_global_load_lds((const __attribute__((address_space(1))) void*)g,
                                     (__attribute__((address_space(3))) void*)l, 16, 0, 0);
}

// ---------------- fused: x max-chunks + fp32 -> hi/lo bf16 split ------------
__global__ __launch_bounds__(256) void k_gpart_cvt(const float* __restrict__ x,
                                                   float* __restrict__ gpart,
                                                   ushort* __restrict__ xh,
                                                   ushort* __restrict__ xl){
    int b = blockIdx.x >> 5, ch = blockIdx.x & 31;
    size_t row0 = (size_t)b*S_ + (size_t)ch*64;
    const float4* xb = (const float4*)(x + row0*DM);
    int t = threadIdx.x;
    float4 m = float4{-3.402823466e38f, -3.402823466e38f, -3.402823466e38f, -3.402823466e38f};
    for(int r = 0; r < 64; r++){
        float4 v = xb[(size_t)r*(DM/4) + t];
        ushort hx = f2b(v.x), hy = f2b(v.y), hz = f2b(v.z), hw = f2b(v.w);
        uint2 H{ (uint)hx | ((uint)hy << 16), (uint)hz | ((uint)hw << 16) };
        uint2 L{ (uint)f2b(v.x - b2f(hx)) | ((uint)f2b(v.y - b2f(hy)) << 16),
                 (uint)f2b(v.z - b2f(hz)) | ((uint)f2b(v.w - b2f(hw)) << 16) };
        ((uint2*)(xh + (row0 + r)*DM))[t] = H;
        ((uint2*)(xl + (row0 + r)*DM))[t] = L;
        m.x = fmaxf(m.x, v.x); m.y = fmaxf(m.y, v.y);
        m.z = fmaxf(m.z, v.z); m.w = fmaxf(m.w, v.w);
    }
    ((float4*)(gpart + (size_t)(b*32 + ch)*DM))[t] = m;
}

// ---------------- pre-split fp32 -> hi/lo bf16 (patt) -----------------------
__global__ __launch_bounds__(256) void k_cvt(const float* __restrict__ src,
                                             ushort* __restrict__ hi,
                                             ushort* __restrict__ lo){
    size_t idx = (size_t)blockIdx.x*256 + threadIdx.x;
    float f[8];
    *(float4*)(f)     = ((const float4*)src)[idx*2];
    *(float4*)(f + 4) = ((const float4*)src)[idx*2 + 1];
    uint4 H, L; cvt8(f, H, L);
    ((uint4*)hi)[idx] = H;
    ((uint4*)lo)[idx] = L;
}

// ---------------- fp32 -> bf16 (hi only, for pout) --------------------------
__global__ __launch_bounds__(256) void k_cvt1(const float* __restrict__ src,
                                              ushort* __restrict__ dst){
    size_t idx = (size_t)blockIdx.x*256 + threadIdx.x;
    float f[8];
    *(float4*)(f)     = ((const float4*)src)[idx*2];
    *(float4*)(f + 4) = ((const float4*)src)[idx*2 + 1];
    uint o[4];
    #pragma unroll
    for(int i = 0; i < 4; i++)
        o[i] = (uint)f2b(f[2*i]) | ((uint)f2b(f[2*i+1]) << 16);
    ((uint4*)dst)[idx] = uint4{o[0], o[1], o[2], o[3]};
}

// ---------------- Router (all fp32) -----------------------------------------
__global__ __launch_bounds__(256) void k_h(const float* __restrict__ gpart,
                                           const float* __restrict__ W1,
                                           const float* __restrict__ b1,
                                           float* __restrict__ h){
    __shared__ float g[DM];
    int b = blockIdx.x >> 3, ig = blockIdx.x & 7;
    int t = threadIdx.x;
    for(int d = t; d < DM; d += 256){
        float m = gpart[(size_t)(b*32)*DM + d];
        for(int c = 1; c < 32; c++) m = fmaxf(m, gpart[(size_t)(b*32 + c)*DM + d]);
        g[d] = m;
    }
    __syncthreads();
    int i  = ig*64 + (t >> 2);
    int dq = (t & 3) * 256;
    const float* wr = W1 + (size_t)i*DM + dq;
    const float* gg = g + dq;
    float s = 0.f;
    for(int d = 0; d < 256; d++) s = fmaf(gg[d], wr[d], s);
    s += __shfl_xor(s, 1);
    s += __shfl_xor(s, 2);
    if((t & 3) == 0) h[b*H2 + i] = gelu_erf(s + b1[i]);
}

__global__ __launch_bounds__(256) void k_query(const float* __restrict__ h,
                                               const float* __restrict__ lng,
                                               const float* __restrict__ lnb,
                                               const float* __restrict__ W2,
                                               const float* __restrict__ b2,
                                               float* __restrict__ query){
    __shared__ float hn[H2];
    __shared__ float red[4];
    int b = blockIdx.x >> 2, qg = blockIdx.x & 3;
    int t = threadIdx.x;
    float v0 = h[b*H2 + t], v1 = h[b*H2 + 256 + t];
    float s = v0 + v1;
    for(int o = 32; o > 0; o >>= 1) s += __shfl_down(s, o);
    if((t & 63) == 0) red[t >> 6] = s;
    __syncthreads();
    float mean = (red[0] + red[1] + red[2] + red[3]) * (1.f/H2);
    __syncthreads();
    float d0 = v0 - mean, d1 = v1 - mean;
    float sq = d0*d0 + d1*d1;
    for(int o = 32; o > 0; o >>= 1) sq += __shfl_down(sq, o);
    if((t & 63) == 0) red[t >> 6] = sq;
    __syncthreads();
    float var  = (red[0] + red[1] + red[2] + red[3]) * (1.f/H2);
    float rstd = rsqrtf(var + 1e-5f);
    hn[t]       = d0*rstd*lng[t]       + lnb[t];
    hn[256 + t] = d1*rstd*lng[256 + t] + lnb[256 + t];
    __syncthreads();
    int q  = qg*64 + (t >> 2);
    int iq = (t & 3) * 128;
    const float* wr = W2 + (size_t)q*H2 + iq;
    float acc = 0.f;
    for(int i2 = 0; i2 < 128; i2++) acc = fmaf(hn[iq + i2], wr[i2], acc);
    acc += __shfl_xor(acc, 1);
    acc += __shfl_xor(acc, 2);
    if((t & 3) == 0) query[b*DR + q] = acc + b2[q];
}

__global__ __launch_bounds__(256) void k_logits(const float* __restrict__ query,
                                                const float* __restrict__ nk,
                                                float* __restrict__ logits){
    __shared__ float q[DR];
    int b = blockIdx.x >> 4, ng = blockIdx.x & 15;
    int t = threadIdx.x;
    if(t < DR) q[t] = query[b*DR + t];
    __syncthreads();
    int n = ng*256 + t;
    const float* kr = nk + (size_t)n*DR;
    float s = 0.f;
    for(int i = 0; i < DR; i++) s = fmaf(q[i], kr[i], s);
    logits[b*NI + n] = s * 0.0625f;
}

// ------- Top-k SET selection, SORTED ascending output (scan-based) ----------
template<int N_, int KSEL>
__global__ __launch_bounds__(256) void k_topk(const float* __restrict__ vals,
                                              int* __restrict__ idxout){
    __shared__ unsigned u[N_];
    __shared__ int redc[4];
    __shared__ int sc[256];
    int t = threadIdx.x;
    size_t vbase = (size_t)blockIdx.x * N_;
    size_t obase = (size_t)blockIdx.x * KSEL;
    for(int i = t; i < N_; i += 256){
        unsigned bits = __float_as_uint(vals[vbase + i]);
        u[i] = (bits & 0x80000000u) ? ~bits : (bits | 0x80000000u);
    }
    __syncthreads();
    unsigned lo = 0u, hi = 0xFFFFFFFFu;
    while(lo < hi){
        unsigned mid = lo + (unsigned)((((unsigned long long)(hi - lo)) + 1ull) >> 1);
        int c = 0;
        for(int i = t; i < N_; i += 256) c += (u[i] >= mid) ? 1 : 0;
        for(int o = 32; o > 0; o >>= 1) c += __shfl_down(c, o);
        if((t & 63) == 0) redc[t >> 6] = c;
        __syncthreads();
        int tot = redc[0] + redc[1] + redc[2] + redc[3];
        if(tot >= KSEL) lo = mid; else hi = mid - 1;
        __syncthreads();
    }
    unsigned T = lo;
    const int PER = N_ / 256;
    int base = t * PER;
    int lgt = 0, leq = 0;
    for(int j = 0; j < PER; j++){
        unsigned v = u[base + j];
        lgt += (v > T) ? 1 : 0; leq += (v == T) ? 1 : 0;
    }
    sc[t] = (lgt << 16) | leq;
    __syncthreads();
    for(int o = 1; o < 256; o <<= 1){
        int add = (t >= o) ? sc[t - o] : 0;
        __syncthreads();
        sc[t] += add;
        __syncthreads();
    }
    int need = KSEL - (sc[255] >> 16);
    int ex = (t == 0) ? 0 : sc[t - 1];
    int pos = (ex >> 16) + ((ex & 0xffff) < need ? (ex & 0xffff) : need);
    int eq = ex & 0xffff;
    for(int j = 0; j < PER; j++){
        unsigned v = u[base + j];
        if(v > T){ idxout[obase + pos++] = base + j; }
        else if(v == T){ if(eq < need){ idxout[obase + pos++] = base + j; } eq++; }
    }
}

// ------- GEMM1 (G batches): split(gelu(x_b @ patt[iidx_b]^T)) -> selh/sell --
__global__ __launch_bounds__(256) void k_gemm1(const ushort* __restrict__ xh,
                                               const ushort* __restrict__ xl,
                                               const ushort* __restrict__ ph,
                                               const ushort* __restrict__ pl,
                                               const int* __restrict__ iidx,
                                               ushort* __restrict__ selh,
                                               ushort* __restrict__ sell, int b0){
    __shared__ __align__(16) ushort Ah[2][128*32], Al[2][128*32], Bh[2][128*32], Bl[2][128*32];
    __shared__ int rowmap[128];
    int t = threadIdx.x;
    int g = blockIdx.x >> 8, rest = blockIdx.x & 255;
    int b = b0 + g;
    int mb = rest >> 4, nb = rest & 15;
    int m0 = mb*128, n0 = nb*128;
    ushort* selh_g = selh + (size_t)g*S_*KI;
    ushort* sell_g = sell + (size_t)g*S_*KI;
    if(t < 128) rowmap[t] = iidx[(size_t)b*KI + n0 + t];
    __syncthreads();
    int w = t >> 6, l = t & 63;
    int lr = l >> 2, lc = l & 3;
    int r0 = 32*w + lr, r1 = r0 + 16;
    const ushort* pAh0 = xh + ((size_t)b*S_ + m0 + r0)*DM + lc*8;
    const ushort* pAh1 = xh + ((size_t)b*S_ + m0 + r1)*DM + lc*8;
    const ushort* pAl0 = xl + ((size_t)b*S_ + m0 + r0)*DM + lc*8;
    const ushort* pAl1 = xl + ((size_t)b*S_ + m0 + r1)*DM + lc*8;
    const ushort* pBh0 = ph + (size_t)rowmap[r0]*DM + lc*8;
    const ushort* pBh1 = ph + (size_t)rowmap[r1]*DM + lc*8;
    const ushort* pBl0 = pl + (size_t)rowmap[r0]*DM + lc*8;
    const ushort* pBl1 = pl + (size_t)rowmap[r1]*DM + lc*8;
    int d0 = w*1024, d1 = d0 + 512;
    #define STG1(BUF, KO) do{ \
        gload_lds16(pAh0 + (KO), &Ah[BUF][d0]); \
        gload_lds16(pAh1 + (KO), &Ah[BUF][d1]); \
        gload_lds16(pAl0 + (KO), &Al[BUF][d0]); \
        gload_lds16(pAl1 + (KO), &Al[BUF][d1]); \
        gload_lds16(pBh0 + (KO), &Bh[BUF][d0]); \
        gload_lds16(pBh1 + (KO), &Bh[BUF][d1]); \
        gload_lds16(pBl0 + (KO), &Bl[BUF][d0]); \
        gload_lds16(pBl1 + (KO), &Bl[BUF][d1]); \
    }while(0)
    STG1(0, 0);
    int lm = l & 15, q = l >> 4;
    int mbase = (w >> 1)*64, nbase = (w & 1)*64;
    f32x4 acc[4][4];
    #pragma unroll
    for(int i = 0; i < 4; i++)
      #pragma unroll
      for(int j = 0; j < 4; j++) acc[i][j] = f32x4{0.f,0.f,0.f,0.f};
    int cur = 0;
    for(int k0 = 0; k0 < DM; k0 += 32){
        if(k0 + 32 < DM){
            STG1(cur^1, k0 + 32);
            asm volatile("s_waitcnt vmcnt(8)" ::: "memory");
        }else{
            asm volatile("s_waitcnt vmcnt(0)" ::: "memory");
        }
        __builtin_amdgcn_s_barrier();
        asm volatile("" ::: "memory");
        bf16x8 ahf[4], alf[4];
        #pragma unroll
        for(int mt = 0; mt < 4; mt++){
            ahf[mt] = *(const bf16x8*)(&Ah[cur][(mbase + mt*16 + lm)*32 + q*8]);
            alf[mt] = *(const bf16x8*)(&Al[cur][(mbase + mt*16 + lm)*32 + q*8]);
        }
        __builtin_amdgcn_s_setprio(1);
        #pragma unroll
        for(int nt = 0; nt < 4; nt++){
            bf16x8 bhf = *(const bf16x8*)(&Bh[cur][(nbase + nt*16 + lm)*32 + q*8]);
            bf16x8 blf = *(const bf16x8*)(&Bl[cur][(nbase + nt*16 + lm)*32 + q*8]);
            #pragma unroll
            for(int mt = 0; mt < 4; mt++){
                acc[mt][nt] = __builtin_amdgcn_mfma_f32_16x16x32_bf16(ahf[mt], bhf, acc[mt][nt], 0, 0, 0);
                acc[mt][nt] = __builtin_amdgcn_mfma_f32_16x16x32_bf16(ahf[mt], blf, acc[mt][nt], 0, 0, 0);
                acc[mt][nt] = __builtin_amdgcn_mfma_f32_16x16x32_bf16(alf[mt], bhf, acc[mt][nt], 0, 0, 0);
            }
        }
        __builtin_amdgcn_s_setprio(0);
        asm volatile("s_waitcnt lgkmcnt(0)" ::: "memory");
        __builtin_amdgcn_s_barrier();
        asm volatile("" ::: "memory");
        cur ^= 1;
    }
    #undef STG1
    #pragma unroll
    for(int mt = 0; mt < 4; mt++)
      #pragma unroll
      for(int nt = 0; nt < 4; nt++){
        int col = n0 + nbase + nt*16 + lm;
        #pragma unroll
        for(int i = 0; i < 4; i++){
            int row = m0 + mbase + mt*16 + q*4 + i;
            float gv = gelu_erf(acc[mt][nt][i]);
            ushort hbits = f2b(gv);
            selh_g[(size_t)row*KI + col] = hbits;
            sell_g[(size_t)row*KI + col] = f2b(gv - b2f(hbits));
        }
      }
}

// ------- Gather (G batches): split pw columns -> wh/wl; zero scores ---------
// Vectorized: 8 consecutive j per thread, uint4 stores, reg-held indices.
__global__ __launch_bounds__(256) void k_gather_wsel(const float* __restrict__ pw,
                                                     const int* __restrict__ iidx,
                                                     ushort* __restrict__ wh,
                                                     ushort* __restrict__ wl,
                                                     float* __restrict__ scores, int b0){
    int g = blockIdx.x >> 8, pc = blockIdx.x & 255;
    int b = b0 + g;
    ushort* wh_g = wh + (size_t)g*NP*KI;
    ushort* wl_g = wl + (size_t)g*NP*KI;
    int t = threadIdx.x;
    if(t < 8) scores[(size_t)b*NP + pc*8 + t] = 0.f;
    int j0 = t*8;
    int k8[8];
    *(int4*)(k8)     = *(const int4*)(iidx + (size_t)b*KI + j0);
    *(int4*)(k8 + 4) = *(const int4*)(iidx + (size_t)b*KI + j0 + 4);
    for(int r2 = 0; r2 < 8; r2++){
        int p = pc*8 + r2;
        const float* row = pw + (size_t)p*NI;
        uint hh[4], ll[4];
        #pragma unroll
        for(int i = 0; i < 4; i++){
            float v0 = row[k8[2*i]], v1 = row[k8[2*i+1]];
            ushort h0 = f2b(v0), h1 = f2b(v1);
            hh[i] = (uint)h0 | ((uint)h1 << 16);
            ll[i] = (uint)f2b(v0 - b2f(h0)) | ((uint)f2b(v1 - b2f(h1)) << 16);
        }
        *(uint4*)(wh_g + (size_t)p*KI + j0) = uint4{hh[0],hh[1],hh[2],hh[3]};
        *(uint4*)(wl_g + (size_t)p*KI + j0) = uint4{ll[0],ll[1],ll[2],ll[3]};
    }
}

// ------- GEMM2 (G batches): acts=gelu(selin @ wsel^T) bf16 + col sums -------
__global__ __launch_bounds__(256) void k_gemm2(const ushort* __restrict__ selh,
                                               const ushort* __restrict__ sell,
                                               const ushort* __restrict__ wh,
                                               const ushort* __restrict__ wl,
                                               ushort* __restrict__ acts,
                                               float* __restrict__ scores, int b0){
    __shared__ __align__(16) ushort Ah[2][128*32], Al[2][128*32], Bh[2][128*32], Bl[2][128*32];
    __shared__ float colsum[128];
    int t = threadIdx.x;
    int g = blockIdx.x >> 8, rest = blockIdx.x & 255;
    int b = b0 + g;
    int mb = rest >> 4, nb = rest & 15;
    int m0 = mb*128, n0 = nb*128;
    const ushort* selh_g = selh + (size_t)g*S_*KI;
    const ushort* sell_g = sell + (size_t)g*S_*KI;
    const ushort* wh_g   = wh   + (size_t)g*NP*KI;
    const ushort* wl_g   = wl   + (size_t)g*NP*KI;
    ushort* acts_g = acts + (size_t)g*S_*NP;
    int w = t >> 6, l = t & 63;
    int lr = l >> 2, lc = l & 3;
    int r0 = 32*w + lr, r1 = r0 + 16;
    const ushort* pAh0 = selh_g + (size_t)(m0 + r0)*KI + lc*8;
    const ushort* pAh1 = selh_g + (size_t)(m0 + r1)*KI + lc*8;
    const ushort* pAl0 = sell_g + (size_t)(m0 + r0)*KI + lc*8;
    const ushort* pAl1 = sell_g + (size_t)(m0 + r1)*KI + lc*8;
    const ushort* pBh0 = wh_g + (size_t)(n0 + r0)*KI + lc*8;
    const ushort* pBh1 = wh_g + (size_t)(n0 + r1)*KI + lc*8;
    const ushort* pBl0 = wl_g + (size_t)(n0 + r0)*KI + lc*8;
    const ushort* pBl1 = wl_g + (size_t)(n0 + r1)*KI + lc*8;
    int d0 = w*1024, d1 = d0 + 512;
    #define STG2(BUF, KO) do{ \
        gload_lds16(pAh0 + (KO), &Ah[BUF][d0]); \
        gload_lds16(pAh1 + (KO), &Ah[BUF][d1]); \
        gload_lds16(pAl0 + (KO), &Al[BUF][d0]); \
        gload_lds16(pAl1 + (KO), &Al[BUF][d1]); \
        gload_lds16(pBh0 + (KO), &Bh[BUF][d0]); \
        gload_lds16(pBh1 + (KO), &Bh[BUF][d1]); \
        gload_lds16(pBl0 + (KO), &Bl[BUF][d0]); \
        gload_lds16(pBl1 + (KO), &Bl[BUF][d1]); \
    }while(0)
    STG2(0, 0);
    int lm = l & 15, q = l >> 4;
    int mbase = (w >> 1)*64, nbase = (w & 1)*64;
    f32x4 acc[4][4];
    #pragma unroll
    for(int i = 0; i < 4; i++)
      #pragma unroll
      for(int j = 0; j < 4; j++) acc[i][j] = f32x4{0.f,0.f,0.f,0.f};
    int cur = 0;
    for(int k0 = 0; k0 < KI; k0 += 32){
        if(k0 + 32 < KI){
            STG2(cur^1, k0 + 32);
            asm volatile("s_waitcnt vmcnt(8)" ::: "memory");
        }else{
            asm volatile("s_waitcnt vmcnt(0)" ::: "memory");
        }
        __builtin_amdgcn_s_barrier();
        asm volatile("" ::: "memory");
        bf16x8 ahf[4], alf[4];
        #pragma unroll
        for(int mt = 0; mt < 4; mt++){
            ahf[mt] = *(const bf16x8*)(&Ah[cur][(mbase + mt*16 + lm)*32 + q*8]);
            alf[mt] = *(const bf16x8*)(&Al[cur][(mbase + mt*16 + lm)*32 + q*8]);
        }
        __builtin_amdgcn_s_setprio(1);
        #pragma unroll
        for(int nt = 0; nt < 4; nt++){
            bf16x8 bhf = *(const bf16x8*)(&Bh[cur][(nbase + nt*16 + lm)*32 + q*8]);
            bf16x8 blf = *(const bf16x8*)(&Bl[cur][(nbase + nt*16 + lm)*32 + q*8]);
            #pragma unroll
            for(int mt = 0; mt < 4; mt++){
                acc[mt][nt] = __builtin_amdgcn_mfma_f32_16x16x32_bf16(ahf[mt], bhf, acc[mt][nt], 0, 0, 0);
                acc[mt][nt] = __builtin_amdgcn_mfma_f32_16x16x32_bf16(ahf[mt], blf, acc[mt][nt], 0, 0, 0);
                acc[mt][nt] = __builtin_amdgcn_mfma_f32_16x16x32_bf16(alf[mt], bhf, acc[mt][nt], 0, 0, 0);
            }
        }
        __builtin_amdgcn_s_setprio(0);
        asm volatile("s_waitcnt lgkmcnt(0)" ::: "memory");
        __builtin_amdgcn_s_barrier();
        asm volatile("" ::: "memory");
        cur ^= 1;
    }
    #undef STG2
    if(t < 128) colsum[t] = 0.f;
    __syncthreads();
    #pragma unroll
    for(int mt = 0; mt < 4; mt++)
      #pragma unroll
      for(int nt = 0; nt < 4; nt++){
        int cb = nbase + nt*16 + lm;
        float s4 = 0.f;
        #pragma unroll
        for(int i = 0; i < 4; i++){
            int row = m0 + mbase + mt*16 + q*4 + i;
            float gv = gelu_erf(acc[mt][nt][i]);
            s4 += gv;
            acts_g[(size_t)row*NP + n0 + cb] = f2b(gv);
        }
        atomicAdd(&colsum[cb], s4);
      }
    __syncthreads();
    if(t < 128) atomicAdd(&scores[(size_t)b*NP + n0 + t], colsum[t]);
}

// ------- Gather (G batches): selacts[s][j] = acts[s][pix[j]] ----------------
// Vectorized: 4 consecutive j per thread, uint2 stores, reg-held indices.
__global__ __launch_bounds__(256) void k_gather_selacts(const ushort* __restrict__ acts,
                                                        const int* __restrict__ pidx,
                                                        ushort* __restrict__ selacts, int b0){
    int g = blockIdx.x >> 6, sc_ = blockIdx.x & 63;
    int b = b0 + g;
    const ushort* acts_g = acts + (size_t)g*S_*NP;
    ushort* selacts_g = selacts + (size_t)g*S_*KP;
    int t = threadIdx.x;
    int j0 = t*4;
    int4 p4 = *(const int4*)(pidx + (size_t)b*KP + j0);
    const ushort* Ab = acts_g    + ((size_t)sc_*32)*NP;
    ushort*       Ob = selacts_g + ((size_t)sc_*32)*KP;
    for(int r2 = 0; r2 < 32; r2++){
        const ushort* Ar = Ab + (size_t)r2*NP;
        ushort o0 = Ar[p4.x], o1 = Ar[p4.y], o2 = Ar[p4.z], o3 = Ar[p4.w];
        uint2 ov{ (uint)o0 | ((uint)o1 << 16), (uint)o2 | ((uint)o3 << 16) };
        *(uint2*)(Ob + (size_t)r2*KP + j0) = ov;
    }
}

// ------- GEMM3 (G batches): out_b = selacts(bf16) @ poutb[pix] --------------
// A via global_load_lds dbuf; B (pre-cvt bf16) reg-staged + transpose store.
__global__ __launch_bounds__(256) void k_gemm3(const ushort* __restrict__ selacts,
                                               const ushort* __restrict__ poutb,
                                               const int* __restrict__ pidx,
                                               float* __restrict__ out, int b0){
    __shared__ __align__(16) ushort As[2][128*32];
    __shared__ __align__(16) ushort Bs[2][128*LDW];
    __shared__ int pix[KP];
    int t = threadIdx.x;
    int g = blockIdx.x >> 7, rest = blockIdx.x & 127;
    int b = b0 + g;
    int mb = rest >> 3, nb = rest & 7;
    int m0 = mb*128, n0 = nb*128;
    const ushort* sel_g = selacts + (size_t)g*S_*KP;
    int w = t >> 6, l = t & 63;
    int lr = l >> 2, lc = l & 3;
    int r0 = 32*w + lr, r1 = r0 + 16;
    const ushort* pA0 = sel_g + (size_t)(m0 + r0)*KP + lc*8;
    const ushort* pA1 = sel_g + (size_t)(m0 + r1)*KP + lc*8;
    int d0 = w*1024, d1 = d0 + 512;
    gload_lds16(pA0, &As[0][d0]);
    gload_lds16(pA1, &As[0][d1]);
    for(int i = t; i < KP; i += 256) pix[i] = pidx[(size_t)b*KP + i];
    __syncthreads();
    int kk = t >> 3, nc = (t & 7)*16;
    uint4 B0, B1;
    {
        const ushort* bg = poutb + (size_t)pix[kk]*DM + n0 + nc;
        B0 = *(const uint4*)(bg); B1 = *(const uint4*)(bg + 8);
    }
    int lm = l & 15, q = l >> 4;
    int mbase = (w >> 1)*64, nbase = (w & 1)*64;
    f32x4 acc[4][4];
    #pragma unroll
    for(int i = 0; i < 4; i++)
      #pragma unroll
      for(int j = 0; j < 4; j++) acc[i][j] = f32x4{0.f,0.f,0.f,0.f};
    for(int k0 = 0; k0 < KP; k0 += 32){
        int cur = (k0 >> 5) & 1;
        // phase1: B regs -> Bs[cur] (transpose); prefetch A(k0+32) -> As[cur^1]
        {
            const ushort* pb0 = (const ushort*)&B0;
            const ushort* pb1 = (const ushort*)&B1;
            #pragma unroll
            for(int c = 0; c < 8; c++) Bs[cur][(nc + c)*LDW + kk]     = pb0[c];
            #pragma unroll
            for(int c = 0; c < 8; c++) Bs[cur][(nc + 8 + c)*LDW + kk] = pb1[c];
        }
        if(k0 + 32 < KP){
            gload_lds16(pA0 + (k0 + 32), &As[cur^1][d0]);
            gload_lds16(pA1 + (k0 + 32), &As[cur^1][d1]);
            asm volatile("s_waitcnt vmcnt(2)" ::: "memory");
        }else{
            asm volatile("s_waitcnt vmcnt(0)" ::: "memory");
        }
        asm volatile("s_waitcnt lgkmcnt(0)" ::: "memory");
        __builtin_amdgcn_s_barrier();
        asm volatile("" ::: "memory");
        // phase2: load next B regs (overlaps MFMA); read frags; MFMA
        if(k0 + 32 < KP){
            const ushort* bg = poutb + (size_t)pix[k0 + 32 + kk]*DM + n0 + nc;
            B0 = *(const uint4*)(bg); B1 = *(const uint4*)(bg + 8);
        }
        bf16x8 af[4];
        #pragma unroll
        for(int mt = 0; mt < 4; mt++)
            af[mt] = *(const bf16x8*)(&As[cur][(mbase + mt*16 + lm)*32 + q*8]);
        __builtin_amdgcn_s_setprio(1);
        #pragma unroll
        for(int nt = 0; nt < 4; nt++){
            bf16x8 bf = *(const bf16x8*)(&Bs[cur][(nbase + nt*16 + lm)*LDW + q*8]);
            #pragma unroll
            for(int mt = 0; mt < 4; mt++)
                acc[mt][nt] = __builtin_amdgcn_mfma_f32_16x16x32_bf16(af[mt], bf, acc[mt][nt], 0, 0, 0);
        }
        __builtin_amdgcn_s_setprio(0);
        asm volatile("s_waitcnt lgkmcnt(0)" ::: "memory");
        __builtin_amdgcn_s_barrier();
        asm volatile("" ::: "memory");
    }
    float* Cb = out + (size_t)b*S_*DM;
    #pragma unroll
    for(int mt = 0; mt < 4; mt++)
      #pragma unroll
      for(int nt = 0; nt < 4; nt++){
        int col = n0 + nbase + nt*16 + lm;
        #pragma unroll
        for(int i = 0; i < 4; i++){
            int row = m0 + mbase + mt*16 + q*4 + i;
            Cb[(size_t)row*DM + col] = acc[mt][nt][i];
        }
      }
}

// ---------------- launch ----------------------------------------------------
extern "C" void kernel_launch(void* const* d_in, const int* in_sizes, int n_in,
                              void* d_out, int out_size, void* d_ws, size_t ws_size,
                              hipStream_t stream){
    const float* x    = (const float*)d_in[0];
    const float* W1   = (const float*)d_in[3];
    const float* b1   = (const float*)d_in[4];
    const float* lng  = (const float*)d_in[5];
    const float* lnb  = (const float*)d_in[6];
    const float* W2   = (const float*)d_in[7];
    const float* b2   = (const float*)d_in[8];
    const float* nk   = (const float*)d_in[9];
    const float* patt = (const float*)d_in[10];
    const float* pw   = (const float*)d_in[11];
    const float* pout = (const float*)d_in[12];
    float* out = (float*)d_out;

    auto al256 = [](size_t v){ return (v + 255) & ~(size_t)255; };
    const size_t fixed =
        al256((size_t)B_*32*DM*4) + al256((size_t)B_*H2*4) + al256((size_t)B_*DR*4) +
        al256((size_t)B_*NI*4)    + al256((size_t)B_*KI*4) + al256((size_t)B_*NP*4) +
        al256((size_t)B_*KP*4) +
        2*al256((size_t)B_*S_*DM*2) + 2*al256((size_t)NI*DM*2) + al256((size_t)NP*DM*2);
    const size_t perb = (size_t)S_*KI*2*2 + (size_t)NP*KI*2*2 + (size_t)S_*NP*2 + (size_t)S_*KP*2 + 6*256;
    int G = 8;                                   // ws_size-constant across calls -> capture-safe
    while(G > 1 && fixed + (size_t)G*perb > ws_size) G >>= 1;
    if(fixed + (size_t)G*perb > ws_size) return; // clean-fail guard

    char* wsp = (char*)d_ws;
    size_t off = 0;
    auto alloc = [&](size_t bytes) -> void* {
        void* p = wsp + off;
        off += (bytes + 255) & ~(size_t)255;
        return p;
    };
    float*  gpart   = (float*) alloc((size_t)B_*32*DM*4);
    float*  h       = (float*) alloc((size_t)B_*H2*4);
    float*  query   = (float*) alloc((size_t)B_*DR*4);
    float*  logits  = (float*) alloc((size_t)B_*NI*4);
    int*    iidx    = (int*)   alloc((size_t)B_*KI*4);
    float*  scores  = (float*) alloc((size_t)B_*NP*4);
    int*    pidx    = (int*)   alloc((size_t)B_*KP*4);
    ushort* xh      = (ushort*)alloc((size_t)B_*S_*DM*2);
    ushort* xl      = (ushort*)alloc((size_t)B_*S_*DM*2);
    ushort* patth   = (ushort*)alloc((size_t)NI*DM*2);
    ushort* pattl   = (ushort*)alloc((size_t)NI*DM*2);
    ushort* poutb   = (ushort*)alloc((size_t)NP*DM*2);
    ushort* selh    = (ushort*)alloc((size_t)G*S_*KI*2);
    ushort* sell    = (ushort*)alloc((size_t)G*S_*KI*2);
    ushort* wselh   = (ushort*)alloc((size_t)G*NP*KI*2);
    ushort* wsell   = (ushort*)alloc((size_t)G*NP*KI*2);
    ushort* acts    = (ushort*)alloc((size_t)G*S_*NP*2);
    ushort* selacts = (ushort*)alloc((size_t)G*S_*KP*2);

    dim3 blk(256);
    k_gpart_cvt<<<B_*32, blk, 0, stream>>>(x, gpart, xh, xl);
    k_cvt   <<<(NI*DM/8)/256, blk, 0, stream>>>(patt, patth, pattl);
    k_cvt1  <<<(NP*DM/8)/256, blk, 0, stream>>>(pout, poutb);
    k_h     <<<64,  blk, 0, stream>>>(gpart, W1, b1, h);
    k_query <<<32,  blk, 0, stream>>>(h, lng, lnb, W2, b2, query);
    k_logits<<<128, blk, 0, stream>>>(query, nk, logits);
    k_topk<NI, KI><<<B_, blk, 0, stream>>>(logits, iidx);
    for(int b0 = 0; b0 < B_; b0 += G){
        k_gemm1        <<<G*256, blk, 0, stream>>>(xh, xl, patth, pattl, iidx, selh, sell, b0);
        k_gather_wsel  <<<G*256, blk, 0, stream>>>(pw, iidx, wselh, wsell, scores, b0);
        k_gemm2        <<<G*256, blk, 0, stream>>>(selh, sell, wselh, wsell, acts, scores, b0);
        k_topk<NP, KP> <<<G,     blk, 0, stream>>>(scores + (size_t)b0*NP, pidx + (size_t)b0*KP);
        k_gather_selacts<<<G*64, blk, 0, stream>>>(acts, pidx, selacts, b0);
        k_gemm3        <<<G*128, blk, 0, stream>>>(selacts, poutb, pidx, out, b0);
    }
}